// Round 13
// baseline (124.042 us; speedup 1.0000x reference)
//
#include <hip/hip_runtime.h>
#include <math.h>

// ---------------- static problem structure (LMAX=4, taus=16) ----------------
#define NTRI 42
#define NCH  10752
#define B_SZ 256
#define AH_PL 172032

typedef float    f32x4 __attribute__((ext_vector_type(4)));
typedef _Float16 half8 __attribute__((ext_vector_type(8)));
typedef _Float16 half4 __attribute__((ext_vector_type(4)));
typedef _Float16 f16x2 __attribute__((ext_vector_type(2)));

// triples sorted by (l,l1,l2); CT_T = tile index within degree l
constexpr int CT_L [NTRI]={0,0,0,0,0, 1,1,1,1,1,1,1,1, 2,2,2,2,2,2,2,2,2,2, 3,3,3,3,3,3,3,3,3,3, 4,4,4,4,4,4,4,4,4};
constexpr int CT_L1[NTRI]={0,1,2,3,4, 1,1,2,2,3,3,4,4, 1,2,2,2,3,3,3,4,4,4, 2,2,3,3,3,3,4,4,4,4, 2,3,3,3,4,4,4,4,4};
constexpr int CT_L2[NTRI]={0,1,2,3,4, 0,1,1,2,2,3,3,4, 1,0,1,2,1,2,3,2,3,4, 1,2,0,1,2,3,1,2,3,4, 2,1,2,3,0,1,2,3,4};
constexpr int CT_T [NTRI]={0,1,2,3,4, 0,1,2,3,4,5,6,7, 0,1,2,3,4,5,6,7,8,9, 0,1,2,3,4,5,6,7,8,9, 0,1,2,3,4,5,6,7,8};

constexpr int KL_t[5]    ={1280,2048,2560,2560,2304};   // t_FF[l] (= K per degree)
constexpr int GBASE_t[5] ={0,1280,3328,5888,8448};      // channel base in varsum
constexpr int ROFF_t[5]  ={0,16,64,144,256};            // row offset in 400-row layout
constexpr int NM_t[5]    ={1,3,5,7,9};
// g_ff layout (f16x2 units): [l][b=256][m][c=K]  -- b-major for write locality
constexpr int FFB_t[5]   ={0,327680,1900544,5177344,9764864};
#define FF_TOT 15073280                                  // 60.3 MB of f16x2
// partial planes: plane index == flat job j = PL[l] + T*NM + m
constexpr int PL_t[5]    ={0,5,29,79,149};
#define PART_PL 4096
#define PART_TOT (230*PART_PL)

// runtime tables (blockIdx-indexed)
__device__ const int   dCTL[NTRI]={0,0,0,0,0, 1,1,1,1,1,1,1,1, 2,2,2,2,2,2,2,2,2,2, 3,3,3,3,3,3,3,3,3,3, 4,4,4,4,4,4,4,4,4};
__device__ const int   dCTT[NTRI]={0,1,2,3,4, 0,1,2,3,4,5,6,7, 0,1,2,3,4,5,6,7,8,9, 0,1,2,3,4,5,6,7,8,9, 0,1,2,3,4,5,6,7,8};
__device__ const int   dK[5]   ={1280,2048,2560,2560,2304};
__device__ const int   dWOFF[5]={0,20480,53248,94208,135168};
__device__ const int   dNM[5]  ={1,3,5,7,9};
__device__ const int   dFFB[5] ={0,327680,1900544,5177344,9764864};
__device__ const int   dPL[5]  ={0,5,29,79,149};
__device__ const int   dGB[5]  ={0,1280,3328,5888,8448};
__device__ const int   dROFF[5]={0,16,64,144,256};
__device__ const int   dNT[5]  ={5,8,10,10,9};
__device__ const float dINV[5] ={1.f/256.f,1.f/768.f,1.f/1280.f,1.f/1792.f,1.f/2304.f}; // 1/(256*NM)

// ---------------- device globals ----------------
__device__ float  g_varsum[NCH];                 // zero at load (.bss); k_wn re-zeroes after use
__device__ __align__(16) f16x2  g_ff[FF_TOT];    // unnormalized FF, f16 (re,im)
__device__ __align__(16) f16x2  g_ah[2*AH_PL];   // normalized W frags: plane0=(wr*s,-wi*s), plane1=(wi*s,wr*s)
__device__ float2 g_part[PART_TOT];              // per-tile GEMM partials

// ---------------- compile-time Clebsch-Gordan table ----------------
constexpr double cfact(int n){ double r=1.0; for(int i=2;i<=n;i++) r*=(double)i; return r; }
constexpr double csqrt_(double v){ double x = v>1.0? v:1.0; for(int i=0;i<80;i++) x = 0.5*(x+v/x); return x; }
constexpr double ccg(int j1,int m1,int j2,int m2,int j,int m){
    if(m1+m2!=m) return 0.0;
    double pref = csqrt_((2.0*j+1.0)*cfact(j+j1-j2)*cfact(j-j1+j2)*cfact(j1+j2-j)/cfact(j1+j2+j+1));
    pref *= csqrt_(cfact(j+m)*cfact(j-m)*cfact(j1-m1)*cfact(j1+m1)*cfact(j2-m2)*cfact(j2+m2));
    double s=0.0;
    for(int k=0;k<=j1+j2-j;k++){
        int a=j1-m1-k, bb=j2+m2-k, c=j-j2+m1+k, d=j-j1-m2+k;
        if(a<0||bb<0||c<0||d<0) continue;
        double term = 1.0/(cfact(k)*cfact(j1+j2-j-k)*cfact(a)*cfact(bb)*cfact(c)*cfact(d));
        s += (k&1)? -term : term;
    }
    return pref*s;
}
struct CG81 { float a[81]; };
constexpr CG81 makecg(int l,int l1,int l2){
    CG81 t{};
    const int n1=2*l1+1;
    for(int mi=0;mi<2*l+1;mi++)
        for(int p=0;p<n1;p++){
            const int m=mi-l, m1=p-l1, m2=m-m1;
            if(m2>=-l2 && m2<=l2) t.a[mi*n1+p]=(float)ccg(l1,m1,l2,m2,l,m);
        }
    return t;
}
template<int TR> struct CGC { static constexpr CG81 t = makecg(CT_L[TR],CT_L1[TR],CT_L2[TR]); };

// ---------------- CG product for a channel PAIR (i,j0),(i,j0+1): shared A -----
// c*A hoisted: 2 muls amortized over 2 channels, 2 FMAs per accumulator
// (sign folded into FMA operand -> free VOP3 modifier).
template<int TR>
__device__ __forceinline__ void cg_pair(const float2* __restrict__ sF,
                                        int i, int j0,
                                        float2* __restrict__ ff0,
                                        float2* __restrict__ ff1){
    constexpr int L=CT_L[TR], L1=CT_L1[TR], L2=CT_L2[TR];
    constexpr int N1=2*L1+1, N2=2*L2+1, NM=2*L+1;
    float2 A[N1], B0[N2], B1[N2];
    #pragma unroll
    for(int p=0;p<N1;p++) A[p]=sF[ROFF_t[L1]+i*N1+p];
    #pragma unroll
    for(int q=0;q<N2;q++) B0[q]=sF[ROFF_t[L2]+j0*N2+q];
    #pragma unroll
    for(int q=0;q<N2;q++) B1[q]=sF[ROFF_t[L2]+(j0+1)*N2+q];
    #pragma unroll
    for(int mi=0;mi<NM;mi++){
        float aR0=0.f, aI0=0.f, aR1=0.f, aI1=0.f;
        const int pLo = (mi-L+L1-L2) > 0 ? (mi-L+L1-L2) : 0;
        const int pHi = (mi-L+L1+L2) < 2*L1 ? (mi-L+L1+L2) : 2*L1;
        #pragma unroll
        for(int p=0;p<N1;p++){
            if(p>=pLo && p<=pHi){               // folds at compile time
                const float c = CGC<TR>::t.a[mi*N1+p];   // literal after unroll
                if(c != 0.f){
                    const int q = mi - L - p + L1 + L2;
                    const float cax=c*A[p].x, cay=c*A[p].y;
                    const float2 b0=B0[q], b1=B1[q];
                    aR0 = fmaf(cax,b0.x,aR0); aR0 = fmaf(-cay,b0.y,aR0);
                    aI0 = fmaf(cax,b0.y,aI0); aI0 = fmaf( cay,b0.x,aI0);
                    aR1 = fmaf(cax,b1.x,aR1); aR1 = fmaf(-cay,b1.y,aR1);
                    aI1 = fmaf(cax,b1.y,aI1); aI1 = fmaf( cay,b1.x,aI1);
                }
            }
        }
        ff0[mi]=make_float2(aR0,aI0);
        ff1[mi]=make_float2(aR1,aI1);
    }
}

// ------- kernel 1: CG once -> f16 FF (b-major) + variance atomics -------------
// grid (42 triples, 32 bq of 8 b's). Block stages 8 Fs slabs (25.6 KB LDS).
// Thread = channel PAIR (ch0=2*(t&127), ch0+1) x 4 b's of its half:
//   - A-operand shared across the pair (same i)
//   - per (b,m) store is one 8B f16x4 -> wave writes 512B contiguous
//   - variance via 2 atomicAdds per thread (688K total, cheap per r0)
template<int TR>
__device__ __forceinline__ void cg_one(const float2* __restrict__ sF, int bq, int t){
    constexpr int L=CT_L[TR], NM=2*L+1, T=CT_T[TR], K=KL_t[L];
    constexpr int NMK=NM*K;
    const int half = t>>7, tt = t&127;
    const int ch0 = tt*2;
    const int i = ch0>>4, j0 = ch0&15;
    float n20=0.f, n21=0.f;
    #pragma unroll
    for(int b4=0;b4<4;b4++){
        const int slab = half*4+b4;
        const int b = bq*8 + slab;
        float2 ff0[NM], ff1[NM];
        cg_pair<TR>(sF + slab*400, i, j0, ff0, ff1);
        const int base = FFB_t[L] + b*NMK + T*256 + ch0;   // f16x2 units, even
        #pragma unroll
        for(int m=0;m<NM;m++){
            n20 = fmaf(ff0[m].x,ff0[m].x,n20); n20 = fmaf(ff0[m].y,ff0[m].y,n20);
            n21 = fmaf(ff1[m].x,ff1[m].x,n21); n21 = fmaf(ff1[m].y,ff1[m].y,n21);
            half4 h;
            h[0]=(_Float16)ff0[m].x; h[1]=(_Float16)ff0[m].y;
            h[2]=(_Float16)ff1[m].x; h[3]=(_Float16)ff1[m].y;
            *reinterpret_cast<half4*>(g_ff + base + m*K) = h;   // 8B aligned
        }
    }
    atomicAdd(&g_varsum[GBASE_t[L] + T*256 + ch0    ], n20);
    atomicAdd(&g_varsum[GBASE_t[L] + T*256 + ch0 + 1], n21);
}

template<int TR>
__device__ __forceinline__ void cg_disp(int tr, const float2* sF, int bq, int t){
    if constexpr (TR < NTRI){
        if(tr==TR) cg_one<TR>(sF,bq,t);
        else       cg_disp<TR+1>(tr,sF,bq,t);
    }
}

__global__ void __launch_bounds__(256) k_cg(const float2* __restrict__ Fs){
    __shared__ float4 sF4[1600];                // 8 b-slabs of 400 float2
    const int bq=blockIdx.y, t=threadIdx.x;
    const float4* __restrict__ F4 = reinterpret_cast<const float4*>(Fs) + bq*1600;
    #pragma unroll
    for(int k=0;k<6;k++) sF4[t + k*256] = F4[t + k*256];
    if(t<64) sF4[t+1536] = F4[t+1536];
    __syncthreads();
    cg_disp<0>(blockIdx.x, reinterpret_cast<const float2*>(sF4), bq, t);
}

// ------- kernel 2: bake normalized f16 W-fragments; re-zero varsum ------------
__global__ void __launch_bounds__(256) k_wn(const float2* __restrict__ W2){
    const int tr=blockIdx.x, t=threadIdx.x;
    const int l=dCTL[tr], T=dCTT[tr], K=dK[l];
    const int ch = dGB[l] + T*256 + t;
    const float s = g_varsum[ch];
    g_varsum[ch] = 0.f;                          // re-arm for next launch (no memset dispatch)
    const float invv = 1.f/(sqrtf(s*dINV[l])+1e-5f);
    const int base = dWOFF[l] + T*256 + t;
    #pragma unroll 4
    for(int o=0;o<16;o++){
        const float2 w = W2[base + o*K];
        f16x2 hr, hi;
        hr.x=(_Float16)( w.x*invv); hr.y=(_Float16)(-w.y*invv);
        hi.x=(_Float16)( w.y*invv); hi.y=(_Float16)( w.x*invv);
        g_ah[base + o*K]         = hr;
        g_ah[AH_PL + base + o*K] = hi;
    }
}

// ------- kernel 3: pure MFMA GEMM. 2 b-groups per wave (A-frag reuse) ---------
// job j in [0,230) = (l, T, m); wave handles bg = slot and slot+8.
// Frags (16x16x32): A row = lane&15 (=o), B col = lane&15 (=b_local),
//   identical per-lane k map for A and B -> any k-permute cancels.
//   D: col=lane&15, row=(lane>>4)*4+r  [HW-verified].
__global__ void __launch_bounds__(256) k_mm(){
    const int j=blockIdx.x;
    const int wv=threadIdx.x>>6, lane=threadIdx.x&63;
    const int slot=blockIdx.y*4+wv;             // 0..7
    const int bgA=slot, bgB=slot+8;
    const int l=(j<5)?0:(j<29)?1:(j<79)?2:(j<149)?3:4;
    const int nm=dNM[l];
    const int loc=j-dPL[l];
    const int T=loc/nm, m=loc-T*nm;
    const int K=dK[l];
    const int l15=lane&15, kg=lane>>4;
    const half8* __restrict__ Arp = reinterpret_cast<const half8*>(g_ah + dWOFF[l] + l15*K + T*256 + kg*4);
    const half8* __restrict__ Aip = reinterpret_cast<const half8*>(g_ah + AH_PL + dWOFF[l] + l15*K + T*256 + kg*4);
    const half8* __restrict__ XpA = reinterpret_cast<const half8*>(g_ff + dFFB[l] + (bgA*16+l15)*(nm*K) + m*K + T*256 + kg*4);
    const half8* __restrict__ XpB = reinterpret_cast<const half8*>(g_ff + dFFB[l] + (bgB*16+l15)*(nm*K) + m*K + T*256 + kg*4);
    f32x4 arA={0.f,0.f,0.f,0.f}, aiA={0.f,0.f,0.f,0.f};
    f32x4 arB={0.f,0.f,0.f,0.f}, aiB={0.f,0.f,0.f,0.f};
    #pragma unroll
    for(int ks=0; ks<16; ks++){
        const half8 Ar = Arp[ks*4];             // 16B each, all 16B-aligned
        const half8 Ai = Aip[ks*4];
        const half8 BA = XpA[ks*4];
        const half8 BB = XpB[ks*4];
        arA = __builtin_amdgcn_mfma_f32_16x16x32_f16(Ar, BA, arA, 0,0,0);
        aiA = __builtin_amdgcn_mfma_f32_16x16x32_f16(Ai, BA, aiA, 0,0,0);
        arB = __builtin_amdgcn_mfma_f32_16x16x32_f16(Ar, BB, arB, 0,0,0);
        aiB = __builtin_amdgcn_mfma_f32_16x16x32_f16(Ai, BB, aiB, 0,0,0);
    }
    float2* __restrict__ ppA = g_part + j*PART_PL + bgA*256;
    float2* __restrict__ ppB = g_part + j*PART_PL + bgB*256;
    #pragma unroll
    for(int r=0;r<4;r++){
        ppA[(kg*4+r)*16 + l15] = make_float2(arA[r], aiA[r]);
        ppB[(kg*4+r)*16 + l15] = make_float2(arB[r], aiB[r]);
    }
}

// ------- kernel 4: reduce tile partials -> out --------------------------------
__global__ void __launch_bounds__(448) k_red(float2* __restrict__ out){
    const int b=blockIdx.x, r=threadIdx.x;
    if(r>=400) return;
    const int l = (r<16)?0:(r<64)?1:(r<144)?2:(r<256)?3:4;
    const int om = r - dROFF[l];               // = o*NM + m
    const int nm = dNM[l];
    const int o = om/nm, m = om - o*nm;
    const float2* __restrict__ pp = g_part + (dPL[l]+m)*PART_PL + (b>>4)*256 + o*16 + (b&15);
    float2 s=make_float2(0.f,0.f);
    const int nt=dNT[l];
    for(int T=0;T<nt;T++){
        const float2 v = pp[T*nm*PART_PL];
        s.x+=v.x; s.y+=v.y;
    }
    out[b*400+r]=s;
}

// ---------------- launcher ----------------
extern "C" void kernel_launch(void* const* d_in, const int* in_sizes, int n_in,
                              void* d_out, int out_size, void* d_ws, size_t ws_size,
                              hipStream_t stream){
    const float2* Fs = (const float2*)d_in[0];   // [256,400,2] fp32
    const float2* W  = (const float2*)d_in[1];   // [172032,2]  fp32
    float2* out = (float2*)d_out;                // [256,400,2] fp32

    k_cg <<<dim3(NTRI,32), 256, 0, stream>>>(Fs);
    k_wn <<<dim3(NTRI),    256, 0, stream>>>(W);
    k_mm <<<dim3(230,2),   256, 0, stream>>>();
    k_red<<<dim3(B_SZ),    448, 0, stream>>>(out);
}

// Round 14
// 108.908 us; speedup vs baseline: 1.1390x; 1.1390x over previous
//
#include <hip/hip_runtime.h>
#include <math.h>

// ---------------- static problem structure (LMAX=4, taus=16) ----------------
#define NTRI 42
#define NCH  10752
#define B_SZ 256
#define AH_PL 172032

typedef float    f32x4 __attribute__((ext_vector_type(4)));
typedef _Float16 half8 __attribute__((ext_vector_type(8)));
typedef _Float16 half4 __attribute__((ext_vector_type(4)));
typedef _Float16 f16x2 __attribute__((ext_vector_type(2)));

// triples sorted by (l,l1,l2); CT_T = tile index within degree l
constexpr int CT_L [NTRI]={0,0,0,0,0, 1,1,1,1,1,1,1,1, 2,2,2,2,2,2,2,2,2,2, 3,3,3,3,3,3,3,3,3,3, 4,4,4,4,4,4,4,4,4};
constexpr int CT_L1[NTRI]={0,1,2,3,4, 1,1,2,2,3,3,4,4, 1,2,2,2,3,3,3,4,4,4, 2,2,3,3,3,3,4,4,4,4, 2,3,3,3,4,4,4,4,4};
constexpr int CT_L2[NTRI]={0,1,2,3,4, 0,1,1,2,2,3,3,4, 1,0,1,2,1,2,3,2,3,4, 1,2,0,1,2,3,1,2,3,4, 2,1,2,3,0,1,2,3,4};
constexpr int CT_T [NTRI]={0,1,2,3,4, 0,1,2,3,4,5,6,7, 0,1,2,3,4,5,6,7,8,9, 0,1,2,3,4,5,6,7,8,9, 0,1,2,3,4,5,6,7,8};

constexpr int KL_t[5]    ={1280,2048,2560,2560,2304};   // t_FF[l] (= K per degree)
constexpr int GBASE_t[5] ={0,1280,3328,5888,8448};      // channel base in varsum
constexpr int ROFF_t[5]  ={0,16,64,144,256};            // row offset in 400-row layout
constexpr int NM_t[5]    ={1,3,5,7,9};
constexpr int NT_c[5]    ={5,8,10,10,9};                // tiles per degree
// g_ff layout (f16x2 units): [l][m][T][b=256][c=256]  -- (m,T)-major planes of 256KB;
// a k_cg block (tr,bq) writes 8 KB CONTIGUOUS per m (8 b's x 256 ch) -> HBM write
// granule 1KB -> 8KB (r13 diagnosis: 1KB-granule scatter capped writes at 1.27 TB/s).
// Per-degree totals NM*nt*65536 == NM*K*256: FFB offsets unchanged.
constexpr int FFB_t[5]   ={0,327680,1900544,5177344,9764864};
#define FF_TOT 15073280                                  // 60.3 MB of f16x2
// partial planes: plane index == flat job j = PL[l] + T*NM + m
constexpr int PL_t[5]    ={0,5,29,79,149};
#define PART_PL 4096
#define PART_TOT (230*PART_PL)

// runtime tables (blockIdx-indexed)
__device__ const int   dCTL[NTRI]={0,0,0,0,0, 1,1,1,1,1,1,1,1, 2,2,2,2,2,2,2,2,2,2, 3,3,3,3,3,3,3,3,3,3, 4,4,4,4,4,4,4,4,4};
__device__ const int   dCTT[NTRI]={0,1,2,3,4, 0,1,2,3,4,5,6,7, 0,1,2,3,4,5,6,7,8,9, 0,1,2,3,4,5,6,7,8,9, 0,1,2,3,4,5,6,7,8};
__device__ const int   dK[5]   ={1280,2048,2560,2560,2304};
__device__ const int   dWOFF[5]={0,20480,53248,94208,135168};
__device__ const int   dNM[5]  ={1,3,5,7,9};
__device__ const int   dFFB[5] ={0,327680,1900544,5177344,9764864};
__device__ const int   dPL[5]  ={0,5,29,79,149};
__device__ const int   dGB[5]  ={0,1280,3328,5888,8448};
__device__ const int   dROFF[5]={0,16,64,144,256};
__device__ const int   dNT[5]  ={5,8,10,10,9};
__device__ const float dINV[5] ={1.f/256.f,1.f/768.f,1.f/1280.f,1.f/1792.f,1.f/2304.f}; // 1/(256*NM)

// ---------------- device globals ----------------
__device__ float  g_varsum[NCH];                 // zero at load (.bss); k_wn re-zeroes after use
__device__ __align__(16) f16x2  g_ff[FF_TOT];    // unnormalized FF, f16 (re,im)
__device__ __align__(16) f16x2  g_ah[2*AH_PL];   // normalized W frags: plane0=(wr*s,-wi*s), plane1=(wi*s,wr*s)
__device__ float2 g_part[PART_TOT];              // per-tile GEMM partials

// ---------------- compile-time Clebsch-Gordan table ----------------
constexpr double cfact(int n){ double r=1.0; for(int i=2;i<=n;i++) r*=(double)i; return r; }
constexpr double csqrt_(double v){ double x = v>1.0? v:1.0; for(int i=0;i<80;i++) x = 0.5*(x+v/x); return x; }
constexpr double ccg(int j1,int m1,int j2,int m2,int j,int m){
    if(m1+m2!=m) return 0.0;
    double pref = csqrt_((2.0*j+1.0)*cfact(j+j1-j2)*cfact(j-j1+j2)*cfact(j1+j2-j)/cfact(j1+j2+j+1));
    pref *= csqrt_(cfact(j+m)*cfact(j-m)*cfact(j1-m1)*cfact(j1+m1)*cfact(j2-m2)*cfact(j2+m2));
    double s=0.0;
    for(int k=0;k<=j1+j2-j;k++){
        int a=j1-m1-k, bb=j2+m2-k, c=j-j2+m1+k, d=j-j1-m2+k;
        if(a<0||bb<0||c<0||d<0) continue;
        double term = 1.0/(cfact(k)*cfact(j1+j2-j-k)*cfact(a)*cfact(bb)*cfact(c)*cfact(d));
        s += (k&1)? -term : term;
    }
    return pref*s;
}
struct CG81 { float a[81]; };
constexpr CG81 makecg(int l,int l1,int l2){
    CG81 t{};
    const int n1=2*l1+1;
    for(int mi=0;mi<2*l+1;mi++)
        for(int p=0;p<n1;p++){
            const int m=mi-l, m1=p-l1, m2=m-m1;
            if(m2>=-l2 && m2<=l2) t.a[mi*n1+p]=(float)ccg(l1,m1,l2,m2,l,m);
        }
    return t;
}
template<int TR> struct CGC { static constexpr CG81 t = makecg(CT_L[TR],CT_L1[TR],CT_L2[TR]); };

// ---------------- CG product for a channel PAIR (i,j0),(i,j0+1): shared A -----
// c*A hoisted: 2 muls amortized over 2 channels, 2 FMAs per accumulator
// (sign folded into FMA operand -> free VOP3 modifier).
template<int TR>
__device__ __forceinline__ void cg_pair(const float2* __restrict__ sF,
                                        int i, int j0,
                                        float2* __restrict__ ff0,
                                        float2* __restrict__ ff1){
    constexpr int L=CT_L[TR], L1=CT_L1[TR], L2=CT_L2[TR];
    constexpr int N1=2*L1+1, N2=2*L2+1, NM=2*L+1;
    float2 A[N1], B0[N2], B1[N2];
    #pragma unroll
    for(int p=0;p<N1;p++) A[p]=sF[ROFF_t[L1]+i*N1+p];
    #pragma unroll
    for(int q=0;q<N2;q++) B0[q]=sF[ROFF_t[L2]+j0*N2+q];
    #pragma unroll
    for(int q=0;q<N2;q++) B1[q]=sF[ROFF_t[L2]+(j0+1)*N2+q];
    #pragma unroll
    for(int mi=0;mi<NM;mi++){
        float aR0=0.f, aI0=0.f, aR1=0.f, aI1=0.f;
        const int pLo = (mi-L+L1-L2) > 0 ? (mi-L+L1-L2) : 0;
        const int pHi = (mi-L+L1+L2) < 2*L1 ? (mi-L+L1+L2) : 2*L1;
        #pragma unroll
        for(int p=0;p<N1;p++){
            if(p>=pLo && p<=pHi){               // folds at compile time
                const float c = CGC<TR>::t.a[mi*N1+p];   // literal after unroll
                if(c != 0.f){
                    const int q = mi - L - p + L1 + L2;
                    const float cax=c*A[p].x, cay=c*A[p].y;
                    const float2 b0=B0[q], b1=B1[q];
                    aR0 = fmaf(cax,b0.x,aR0); aR0 = fmaf(-cay,b0.y,aR0);
                    aI0 = fmaf(cax,b0.y,aI0); aI0 = fmaf( cay,b0.x,aI0);
                    aR1 = fmaf(cax,b1.x,aR1); aR1 = fmaf(-cay,b1.y,aR1);
                    aI1 = fmaf(cax,b1.y,aI1); aI1 = fmaf( cay,b1.x,aI1);
                }
            }
        }
        ff0[mi]=make_float2(aR0,aI0);
        ff1[mi]=make_float2(aR1,aI1);
    }
}

// ------- kernel 1: CG once -> f16 FF ([m][T][b][c] layout) + variance atomics -
// grid (42 triples, 32 bq of 8 b's). Block stages 8 Fs slabs (25.6 KB LDS).
// Thread = channel PAIR (ch0=2*(t&127), ch0+1) x 4 b's of its half.
// Per (b,m) a wave-pair writes 512B; the block's 8 b's are ADJACENT -> 8KB
// contiguous per (block, m): write-granule fix for the 1.27 TB/s wall (r13).
template<int TR>
__device__ __forceinline__ void cg_one(const float2* __restrict__ sF, int bq, int t){
    constexpr int L=CT_L[TR], NM=2*L+1, T=CT_T[TR];
    constexpr int MSTR=NT_c[L]*65536;           // m-plane stride in f16x2
    const int half = t>>7, tt = t&127;
    const int ch0 = tt*2;
    const int i = ch0>>4, j0 = ch0&15;
    float n20=0.f, n21=0.f;
    #pragma unroll
    for(int b4=0;b4<4;b4++){
        const int slab = half*4+b4;
        const int b = bq*8 + slab;
        float2 ff0[NM], ff1[NM];
        cg_pair<TR>(sF + slab*400, i, j0, ff0, ff1);
        const int base = FFB_t[L] + T*65536 + b*256 + ch0;   // f16x2 units, even
        #pragma unroll
        for(int m=0;m<NM;m++){
            n20 = fmaf(ff0[m].x,ff0[m].x,n20); n20 = fmaf(ff0[m].y,ff0[m].y,n20);
            n21 = fmaf(ff1[m].x,ff1[m].x,n21); n21 = fmaf(ff1[m].y,ff1[m].y,n21);
            half4 h;
            h[0]=(_Float16)ff0[m].x; h[1]=(_Float16)ff0[m].y;
            h[2]=(_Float16)ff1[m].x; h[3]=(_Float16)ff1[m].y;
            *reinterpret_cast<half4*>(g_ff + base + m*MSTR) = h;   // 8B aligned
        }
    }
    atomicAdd(&g_varsum[GBASE_t[L] + T*256 + ch0    ], n20);
    atomicAdd(&g_varsum[GBASE_t[L] + T*256 + ch0 + 1], n21);
}

template<int TR>
__device__ __forceinline__ void cg_disp(int tr, const float2* sF, int bq, int t){
    if constexpr (TR < NTRI){
        if(tr==TR) cg_one<TR>(sF,bq,t);
        else       cg_disp<TR+1>(tr,sF,bq,t);
    }
}

__global__ void __launch_bounds__(256) k_cg(const float2* __restrict__ Fs){
    __shared__ float4 sF4[1600];                // 8 b-slabs of 400 float2
    const int bq=blockIdx.y, t=threadIdx.x;
    const float4* __restrict__ F4 = reinterpret_cast<const float4*>(Fs) + bq*1600;
    #pragma unroll
    for(int k=0;k<6;k++) sF4[t + k*256] = F4[t + k*256];
    if(t<64) sF4[t+1536] = F4[t+1536];
    __syncthreads();
    cg_disp<0>(blockIdx.x, reinterpret_cast<const float2*>(sF4), bq, t);
}

// ------- kernel 2: bake normalized f16 W-fragments; re-zero varsum ------------
__global__ void __launch_bounds__(256) k_wn(const float2* __restrict__ W2){
    const int tr=blockIdx.x, t=threadIdx.x;
    const int l=dCTL[tr], T=dCTT[tr], K=dK[l];
    const int ch = dGB[l] + T*256 + t;
    const float s = g_varsum[ch];
    g_varsum[ch] = 0.f;                          // re-arm for next launch (no memset dispatch)
    const float invv = 1.f/(sqrtf(s*dINV[l])+1e-5f);
    const int base = dWOFF[l] + T*256 + t;
    #pragma unroll 4
    for(int o=0;o<16;o++){
        const float2 w = W2[base + o*K];
        f16x2 hr, hi;
        hr.x=(_Float16)( w.x*invv); hr.y=(_Float16)(-w.y*invv);
        hi.x=(_Float16)( w.y*invv); hi.y=(_Float16)( w.x*invv);
        g_ah[base + o*K]         = hr;
        g_ah[AH_PL + base + o*K] = hi;
    }
}

// ------- kernel 3: pure MFMA GEMM. 2 b-groups per wave (A-frag reuse) ---------
// job j in [0,230) = (l, T, m); wave handles bg = slot and slot+8.
// B reads from the (m,T) plane: base + (bg*16+l15)*256 + kg*4 -- still 16B
// aligned contiguous per lane. Frag layout as before [HW-verified].
__global__ void __launch_bounds__(256) k_mm(){
    const int j=blockIdx.x;
    const int wv=threadIdx.x>>6, lane=threadIdx.x&63;
    const int slot=blockIdx.y*4+wv;             // 0..7
    const int bgA=slot, bgB=slot+8;
    const int l=(j<5)?0:(j<29)?1:(j<79)?2:(j<149)?3:4;
    const int nm=dNM[l];
    const int loc=j-dPL[l];
    const int T=loc/nm, m=loc-T*nm;
    const int K=dK[l];
    const int l15=lane&15, kg=lane>>4;
    const int pb = dFFB[l] + (m*dNT[l] + T)*65536;          // (m,T) plane base
    const half8* __restrict__ Arp = reinterpret_cast<const half8*>(g_ah + dWOFF[l] + l15*K + T*256 + kg*4);
    const half8* __restrict__ Aip = reinterpret_cast<const half8*>(g_ah + AH_PL + dWOFF[l] + l15*K + T*256 + kg*4);
    const half8* __restrict__ XpA = reinterpret_cast<const half8*>(g_ff + pb + (bgA*16+l15)*256 + kg*4);
    const half8* __restrict__ XpB = reinterpret_cast<const half8*>(g_ff + pb + (bgB*16+l15)*256 + kg*4);
    f32x4 arA={0.f,0.f,0.f,0.f}, aiA={0.f,0.f,0.f,0.f};
    f32x4 arB={0.f,0.f,0.f,0.f}, aiB={0.f,0.f,0.f,0.f};
    #pragma unroll
    for(int ks=0; ks<16; ks++){
        const half8 Ar = Arp[ks*4];             // 16B each, all 16B-aligned
        const half8 Ai = Aip[ks*4];
        const half8 BA = XpA[ks*4];
        const half8 BB = XpB[ks*4];
        arA = __builtin_amdgcn_mfma_f32_16x16x32_f16(Ar, BA, arA, 0,0,0);
        aiA = __builtin_amdgcn_mfma_f32_16x16x32_f16(Ai, BA, aiA, 0,0,0);
        arB = __builtin_amdgcn_mfma_f32_16x16x32_f16(Ar, BB, arB, 0,0,0);
        aiB = __builtin_amdgcn_mfma_f32_16x16x32_f16(Ai, BB, aiB, 0,0,0);
    }
    float2* __restrict__ ppA = g_part + j*PART_PL + bgA*256;
    float2* __restrict__ ppB = g_part + j*PART_PL + bgB*256;
    #pragma unroll
    for(int r=0;r<4;r++){
        ppA[(kg*4+r)*16 + l15] = make_float2(arA[r], aiA[r]);
        ppB[(kg*4+r)*16 + l15] = make_float2(arB[r], aiB[r]);
    }
}

// ------- kernel 4: reduce tile partials -> out --------------------------------
__global__ void __launch_bounds__(448) k_red(float2* __restrict__ out){
    const int b=blockIdx.x, r=threadIdx.x;
    if(r>=400) return;
    const int l = (r<16)?0:(r<64)?1:(r<144)?2:(r<256)?3:4;
    const int om = r - dROFF[l];               // = o*NM + m
    const int nm = dNM[l];
    const int o = om/nm, m = om - o*nm;
    const float2* __restrict__ pp = g_part + (dPL[l]+m)*PART_PL + (b>>4)*256 + o*16 + (b&15);
    float2 s=make_float2(0.f,0.f);
    const int nt=dNT[l];
    for(int T=0;T<nt;T++){
        const float2 v = pp[T*nm*PART_PL];
        s.x+=v.x; s.y+=v.y;
    }
    out[b*400+r]=s;
}

// ---------------- launcher ----------------
extern "C" void kernel_launch(void* const* d_in, const int* in_sizes, int n_in,
                              void* d_out, int out_size, void* d_ws, size_t ws_size,
                              hipStream_t stream){
    const float2* Fs = (const float2*)d_in[0];   // [256,400,2] fp32
    const float2* W  = (const float2*)d_in[1];   // [172032,2]  fp32
    float2* out = (float2*)d_out;                // [256,400,2] fp32

    k_cg <<<dim3(NTRI,32), 256, 0, stream>>>(Fs);
    k_wn <<<dim3(NTRI),    256, 0, stream>>>(W);
    k_mm <<<dim3(230,2),   256, 0, stream>>>();
    k_red<<<dim3(B_SZ),    448, 0, stream>>>(out);
}